// Round 3
// baseline (303.507 us; speedup 1.0000x reference)
//
#include <hip/hip_runtime.h>
#include <hip/hip_bf16.h>

// Static problem dims
#define NS_    2
#define LQ_    1024
#define HIST_  1024
#define LK_    2048
#define NH_    32
#define NKVH_  8
#define HD_    128
#define BS_    64      // kv page size
#define BM_    128     // q rows per workgroup
#define MAXB_  32

typedef __attribute__((ext_vector_type(8))) short short8;
typedef __attribute__((ext_vector_type(4))) float f32x4;

// LDS strides (elements). Bank-audited: all b128 fragment reads land 8 accesses/bank (min).
#define KSTR 136
#define VSTR 72
#define PSTR 72

static __device__ __forceinline__ unsigned short f2bf(float x) {
    __hip_bfloat16 h = __float2bfloat16(x);
    return *(unsigned short*)&h;
}

// ---------------- Pass 1: gather + fp32->bf16 + V-transpose into workspace ----------------
// Kb[grp][tok][d]   grp = seq*8+kvh, tok 0..2047  (bf16)
// Vb[grp][d][tok]   transposed                     (bf16)
__global__ __launch_bounds__(256)
void prep_kv(const float* __restrict__ kc, const float* __restrict__ vc,
             const int* __restrict__ bt,
             unsigned short* __restrict__ Kb, unsigned short* __restrict__ Vb)
{
    __shared__ __align__(16) unsigned short Vt[HD_ * VSTR];
    const int tid = threadIdx.x;
    const int gid = blockIdx.x;            // 512 = seq(2) x kvh(8) x blk(32)
    const int seq = gid >> 8;
    const int kvh = (gid >> 5) & 7;
    const int blk = gid & 31;
    const int ph  = bt[seq * MAXB_ + blk];
    const size_t src = ((size_t)ph * BS_ * NKVH_ + kvh) * HD_;   // float elements
    const int grp = seq * NKVH_ + kvh;

    // K: convert-copy (coalesced float4 loads, 8B bf16 stores)
    {
        const int t8 = tid >> 5, kq = tid & 31;
#pragma unroll
        for (int p = 0; p < 8; ++p) {
            const int tok = p * 8 + t8;
            float4 f = *(const float4*)(kc + src + (size_t)tok * (NKVH_ * HD_) + kq * 4);
            unsigned short u[4] = {f2bf(f.x), f2bf(f.y), f2bf(f.z), f2bf(f.w)};
            *(uint2*)(Kb + ((size_t)grp * LK_ + blk * BS_ + tok) * HD_ + kq * 4) = *(const uint2*)u;
        }
    }
    // V: load fp32, in-register 4-wide transpose to bf16, LDS, then contiguous store
    {
        const int e8 = tid >> 5, dq = tid & 31;
        float4 vr[8];
#pragma unroll
        for (int j = 0; j < 8; ++j)
            vr[j] = *(const float4*)(vc + src + (size_t)(e8 * 8 + j) * (NKVH_ * HD_) + dq * 4);
#pragma unroll
        for (int w2 = 0; w2 < 4; ++w2) {
            unsigned short row[8];
#pragma unroll
            for (int j = 0; j < 8; ++j) {
                float f = (w2 == 0) ? vr[j].x : (w2 == 1) ? vr[j].y : (w2 == 2) ? vr[j].z : vr[j].w;
                row[j] = f2bf(f);
            }
            *(short8*)&Vt[(dq * 4 + w2) * VSTR + e8 * 8] = *(const short8*)row;
        }
    }
    __syncthreads();
#pragma unroll
    for (int u = 0; u < 4; ++u) {
        const int c  = tid + 256 * u;      // 0..1023 chunks of 8 elements
        const int d  = c >> 3, ch = c & 7;
        uint4 x = *(const uint4*)&Vt[d * VSTR + ch * 8];
        *(uint4*)(Vb + ((size_t)grp * HD_ + d) * LK_ + blk * BS_ + ch * 8) = x;
    }
}

// ---------------- Pass 2: fused paged prefill attention ----------------
template<bool PREP>
__global__ __launch_bounds__(256, 2)
void paged_attn(const float* __restrict__ q,
                const unsigned short* __restrict__ Kb,
                const unsigned short* __restrict__ Vb,
                const float* __restrict__ kc,
                const float* __restrict__ vc,
                const int* __restrict__ bt,
                float* __restrict__ out)
{
    __shared__ __align__(16) unsigned short Ksh[BS_ * KSTR];   // 17408 B
    __shared__ __align__(16) unsigned short Vt [HD_ * VSTR];   // 18432 B
    __shared__ __align__(16) unsigned short Psh[BM_ * PSTR];   // 18432 B

    const int tid  = threadIdx.x;
    const int w    = tid >> 6;
    const int lane = tid & 63;
    const int n    = lane & 15;
    const int q4   = lane >> 4;

    // XCD-aware decode: blockIdx.x % 8 == kvh keeps each (kvh) KV slab in one XCD's L2
    const int gid  = blockIdx.x;           // 512
    const int kvh  = gid & 7;
    const int slot = gid >> 3;             // 0..63
    const int seq  = slot >> 5;
    const int sub  = slot & 31;
    const int head = kvh * 4 + (sub & 3);
    const int m0   = (sub >> 2) * BM_;
    const int r0   = m0 + w * 32;
    const int grp  = seq * NKVH_ + kvh;

    // Q fragments fp32 -> bf16: A[m=lane&15][k=quad*8+j]
    short8 qf[2][4];
#pragma unroll
    for (int rt = 0; rt < 2; ++rt) {
        const size_t base = ((size_t)((seq * LQ_ + r0 + rt * 16 + n) * NH_ + head)) * HD_;
#pragma unroll
        for (int c = 0; c < 4; ++c) {
            float4 a = *(const float4*)(q + base + c * 32 + q4 * 8);
            float4 b = *(const float4*)(q + base + c * 32 + q4 * 8 + 4);
            unsigned short u[8] = {f2bf(a.x), f2bf(a.y), f2bf(a.z), f2bf(a.w),
                                   f2bf(b.x), f2bf(b.y), f2bf(b.z), f2bf(b.w)};
            qf[rt][c] = *(const short8*)u;
        }
    }

    f32x4 acc[2][8];
    f32x4 lf[2];
    float mrow[2][4];
#pragma unroll
    for (int rt = 0; rt < 2; ++rt) {
        lf[rt] = (f32x4){0.f, 0.f, 0.f, 0.f};
#pragma unroll
        for (int dt = 0; dt < 8; ++dt) acc[rt][dt] = (f32x4){0.f, 0.f, 0.f, 0.f};
#pragma unroll
        for (int r = 0; r < 4; ++r) mrow[rt][r] = -1e30f;
    }

    const int nb = (HIST_ + m0 + BM_ - 1) / BS_ + 1;

    // ---- staging state (only one set is live per template instantiation) ----
    // PREP: straight bf16 copies
    const int kp_tok = tid >> 2, kp_c0 = tid & 3;
    const int vp_d   = tid >> 1, vp_c0 = tid & 1;
    uint4 kpre[4], vpre[4];
    // DIRECT: fp32 load + cvt + transpose
    const int kd_t8 = tid >> 5, kd_q = tid & 31;
    uint2 kpk[8]; short8 vpk[4];

    auto load_blk = [&](int b) {
        if constexpr (PREP) {
            const size_t kbase = ((size_t)grp * LK_ + b * BS_) * HD_;
#pragma unroll
            for (int p = 0; p < 4; ++p)
                kpre[p] = *(const uint4*)(Kb + kbase + (size_t)kp_tok * HD_ + (kp_c0 + 4 * p) * 8);
            const size_t vbase = (size_t)grp * HD_ * LK_ + b * BS_;
#pragma unroll
            for (int p = 0; p < 4; ++p)
                vpre[p] = *(const uint4*)(Vb + vbase + (size_t)vp_d * LK_ + (vp_c0 + 2 * p) * 8);
        } else {
            const int ph = bt[seq * MAXB_ + b];
            const size_t src = ((size_t)ph * BS_ * NKVH_ + kvh) * HD_;
            float4 kf4[8], vf4[8];
#pragma unroll
            for (int p = 0; p < 8; ++p)
                kf4[p] = *(const float4*)(kc + src + (size_t)(p * 8 + kd_t8) * (NKVH_ * HD_) + kd_q * 4);
#pragma unroll
            for (int j = 0; j < 8; ++j)
                vf4[j] = *(const float4*)(vc + src + (size_t)(kd_t8 * 8 + j) * (NKVH_ * HD_) + kd_q * 4);
#pragma unroll
            for (int p = 0; p < 8; ++p) {
                unsigned short u[4] = {f2bf(kf4[p].x), f2bf(kf4[p].y), f2bf(kf4[p].z), f2bf(kf4[p].w)};
                kpk[p] = *(const uint2*)u;
            }
#pragma unroll
            for (int w2 = 0; w2 < 4; ++w2) {
                unsigned short row[8];
#pragma unroll
                for (int j = 0; j < 8; ++j) {
                    float f = (w2 == 0) ? vf4[j].x : (w2 == 1) ? vf4[j].y : (w2 == 2) ? vf4[j].z : vf4[j].w;
                    row[j] = f2bf(f);
                }
                vpk[w2] = *(const short8*)row;
            }
        }
    };
    auto store_blk = [&]() {
        if constexpr (PREP) {
#pragma unroll
            for (int p = 0; p < 4; ++p)
                *(uint4*)&Ksh[kp_tok * KSTR + (kp_c0 + 4 * p) * 8] = kpre[p];
#pragma unroll
            for (int p = 0; p < 4; ++p)
                *(uint4*)&Vt[vp_d * VSTR + (vp_c0 + 2 * p) * 8] = vpre[p];
        } else {
#pragma unroll
            for (int p = 0; p < 8; ++p)
                *(uint2*)&Ksh[(p * 8 + kd_t8) * KSTR + kd_q * 4] = kpk[p];
#pragma unroll
            for (int w2 = 0; w2 < 4; ++w2)
                *(short8*)&Vt[(kd_q * 4 + w2) * VSTR + kd_t8 * 8] = vpk[w2];
        }
    };

    load_blk(0);
    const float SC = 0.08838834764831845f * 1.4426950408889634f;  // 1/sqrt(128) * log2(e)

    for (int b = 0; b < nb; ++b) {
        __syncthreads();
        store_blk();
        __syncthreads();
        if (b + 1 < nb) load_blk(b + 1);

        if (64 * b <= HIST_ + r0 + 31) {
            f32x4 s[2][4];
#pragma unroll
            for (int rt = 0; rt < 2; ++rt)
#pragma unroll
                for (int kt = 0; kt < 4; ++kt) s[rt][kt] = (f32x4){0.f, 0.f, 0.f, 0.f};
#pragma unroll
            for (int kt = 0; kt < 4; ++kt) {
#pragma unroll
                for (int c = 0; c < 4; ++c) {
                    short8 kf = *(const short8*)&Ksh[(kt * 16 + n) * KSTR + c * 32 + q4 * 8];
#pragma unroll
                    for (int rt = 0; rt < 2; ++rt)
                        s[rt][kt] = __builtin_amdgcn_mfma_f32_16x16x32_bf16(qf[rt][c], kf, s[rt][kt], 0, 0, 0);
                }
            }
            const bool needMask = (64 * b + 63 > HIST_ + r0);
#pragma unroll
            for (int rt = 0; rt < 2; ++rt) {
                float mx[4], al[4];
#pragma unroll
                for (int r = 0; r < 4; ++r) mx[r] = -1e30f;
#pragma unroll
                for (int kt = 0; kt < 4; ++kt) {
#pragma unroll
                    for (int r = 0; r < 4; ++r) {
                        float t = s[rt][kt][r] * SC;
                        if (needMask) {
                            const int key = b * 64 + kt * 16 + n;
                            const int row = r0 + rt * 16 + q4 * 4 + r;
                            if (key > HIST_ + row) t = -1e30f;
                        }
                        s[rt][kt][r] = t;
                        mx[r] = fmaxf(mx[r], t);
                    }
                }
#pragma unroll
                for (int r = 0; r < 4; ++r) {
                    mx[r] = fmaxf(mx[r], __shfl_xor(mx[r], 1));
                    mx[r] = fmaxf(mx[r], __shfl_xor(mx[r], 2));
                    mx[r] = fmaxf(mx[r], __shfl_xor(mx[r], 4));
                    mx[r] = fmaxf(mx[r], __shfl_xor(mx[r], 8));
                    const float mn = fmaxf(mrow[rt][r], mx[r]);
                    al[r] = exp2f(mrow[rt][r] - mn);
                    mrow[rt][r] = mn;
                }
#pragma unroll
                for (int kt = 0; kt < 4; ++kt)
#pragma unroll
                    for (int r = 0; r < 4; ++r) {
                        const float p = exp2f(s[rt][kt][r] - mrow[rt][r]);
                        Psh[(w * 32 + rt * 16 + q4 * 4 + r) * PSTR + kt * 16 + n] = f2bf(p);
                    }
#pragma unroll
                for (int dt = 0; dt < 8; ++dt)
#pragma unroll
                    for (int r = 0; r < 4; ++r) acc[rt][dt][r] *= al[r];
#pragma unroll
                for (int r = 0; r < 4; ++r) lf[rt][r] *= al[r];
            }
            short8 ones;
#pragma unroll
            for (int j = 0; j < 8; ++j) ones[j] = (short)0x3F80;
#pragma unroll
            for (int ks = 0; ks < 2; ++ks) {
                short8 pa[2];
#pragma unroll
                for (int rt = 0; rt < 2; ++rt)
                    pa[rt] = *(const short8*)&Psh[(w * 32 + rt * 16 + n) * PSTR + ks * 32 + q4 * 8];
#pragma unroll
                for (int rt = 0; rt < 2; ++rt)
                    lf[rt] = __builtin_amdgcn_mfma_f32_16x16x32_bf16(pa[rt], ones, lf[rt], 0, 0, 0);
#pragma unroll
                for (int dt = 0; dt < 8; ++dt) {
                    short8 vf = *(const short8*)&Vt[(dt * 16 + n) * VSTR + ks * 32 + q4 * 8];
#pragma unroll
                    for (int rt = 0; rt < 2; ++rt)
                        acc[rt][dt] = __builtin_amdgcn_mfma_f32_16x16x32_bf16(pa[rt], vf, acc[rt][dt], 0, 0, 0);
                }
            }
        }
    }

    // epilogue: O = acc / l (fp32 out)
#pragma unroll
    for (int rt = 0; rt < 2; ++rt) {
        float rl[4];
#pragma unroll
        for (int r = 0; r < 4; ++r) rl[r] = 1.0f / lf[rt][r];
#pragma unroll
        for (int dt = 0; dt < 8; ++dt)
#pragma unroll
            for (int r = 0; r < 4; ++r) {
                const int row = r0 + rt * 16 + q4 * 4 + r;
                out[((size_t)((seq * LQ_ + row) * NH_ + head)) * HD_ + dt * 16 + n] = acc[rt][dt][r] * rl[r];
            }
    }
}

extern "C" void kernel_launch(void* const* d_in, const int* in_sizes, int n_in,
                              void* d_out, int out_size, void* d_ws, size_t ws_size,
                              hipStream_t stream) {
    const float* q  = (const float*)d_in[0];
    const float* kc = (const float*)d_in[1];
    const float* vc = (const float*)d_in[2];
    const int*   bt = (const int*)d_in[5];
    float*      out = (float*)d_out;
    (void)in_sizes; (void)n_in; (void)out_size;

    const size_t kb_elems = (size_t)NS_ * NKVH_ * LK_ * HD_;        // 4.19M
    const size_t need = kb_elems * 2 * sizeof(unsigned short);      // 16.78 MB
    if (ws_size >= need) {
        unsigned short* Kb = (unsigned short*)d_ws;
        unsigned short* Vb = Kb + kb_elems;
        prep_kv<<<512, 256, 0, stream>>>(kc, vc, bt, Kb, Vb);
        paged_attn<true><<<512, 256, 0, stream>>>(q, Kb, Vb, kc, vc, bt, out);
    } else {
        paged_attn<false><<<512, 256, 0, stream>>>(q, nullptr, nullptr, kc, vc, bt, out);
    }
}

// Round 4
// 208.721 us; speedup vs baseline: 1.4541x; 1.4541x over previous
//
#include <hip/hip_runtime.h>
#include <hip/hip_bf16.h>

// Static problem dims
#define NS_    2
#define LQ_    1024
#define HIST_  1024
#define LK_    2048
#define NH_    32
#define NKVH_  8
#define HD_    128
#define BS_    64      // kv page size
#define BM_    128     // q rows per workgroup
#define MAXB_  32

typedef __attribute__((ext_vector_type(8))) short short8;
typedef __attribute__((ext_vector_type(4))) float f32x4;

#define VSTR 72   // prep-internal V transpose tile stride only

static __device__ __forceinline__ unsigned short f2bf(float x) {
    __hip_bfloat16 h = __float2bfloat16(x);
    return *(unsigned short*)&h;
}

static __device__ __forceinline__ void cp16(const void* g, void* l) {
    __builtin_amdgcn_global_load_lds(
        (const __attribute__((address_space(1))) void*)g,
        (__attribute__((address_space(3))) void*)l, 16, 0, 0);
}

template<int CTRL>
static __device__ __forceinline__ float dppmax(float x) {
    int y = __builtin_amdgcn_update_dpp(0, __float_as_int(x), CTRL, 0xf, 0xf, true);
    return fmaxf(x, __int_as_float(y));
}

// ---------------- Pass 1: gather + fp32->bf16 + V-transpose into workspace ----------------
// Kb[grp][tok][d]  (bf16, grp = seq*8+kvh, tok 0..2047)
// Vb[grp][d][tok]  (bf16, transposed)
// 1024 WGs: gid<512 -> K-copy job, gid>=512 -> V-transpose job (more WGs = latency hiding)
__global__ __launch_bounds__(256)
void prep_kv(const float* __restrict__ kc, const float* __restrict__ vc,
             const int* __restrict__ bt,
             unsigned short* __restrict__ Kb, unsigned short* __restrict__ Vb)
{
    __shared__ __align__(16) unsigned short Vt[HD_ * VSTR];
    const int tid = threadIdx.x;
    const int gid = blockIdx.x & 511;
    const int seq = gid >> 8;
    const int kvh = (gid >> 5) & 7;
    const int blk = gid & 31;
    const int ph  = bt[seq * MAXB_ + blk];
    const size_t src = ((size_t)ph * BS_ * NKVH_ + kvh) * HD_;   // float elements
    const int grp = seq * NKVH_ + kvh;

    if (blockIdx.x < 512) {
        // K: convert-copy (coalesced float4 loads, 8B bf16 stores)
        const int t8 = tid >> 5, kq = tid & 31;
#pragma unroll
        for (int p = 0; p < 8; ++p) {
            const int tok = p * 8 + t8;
            float4 f = *(const float4*)(kc + src + (size_t)tok * (NKVH_ * HD_) + kq * 4);
            unsigned short u[4] = {f2bf(f.x), f2bf(f.y), f2bf(f.z), f2bf(f.w)};
            *(uint2*)(Kb + ((size_t)grp * LK_ + blk * BS_ + tok) * HD_ + kq * 4) = *(const uint2*)u;
        }
    } else {
        // V: load fp32, register 4-wide transpose to bf16 via LDS, contiguous store
        const int e8 = tid >> 5, dq = tid & 31;
        float4 vr[8];
#pragma unroll
        for (int j = 0; j < 8; ++j)
            vr[j] = *(const float4*)(vc + src + (size_t)(e8 * 8 + j) * (NKVH_ * HD_) + dq * 4);
#pragma unroll
        for (int w2 = 0; w2 < 4; ++w2) {
            unsigned short row[8];
#pragma unroll
            for (int j = 0; j < 8; ++j) {
                float f = (w2 == 0) ? vr[j].x : (w2 == 1) ? vr[j].y : (w2 == 2) ? vr[j].z : vr[j].w;
                row[j] = f2bf(f);
            }
            *(short8*)&Vt[(dq * 4 + w2) * VSTR + e8 * 8] = *(const short8*)row;
        }
        __syncthreads();
#pragma unroll
        for (int u = 0; u < 4; ++u) {
            const int c  = tid + 256 * u;      // 0..1023 chunks of 8 elements
            const int d  = c >> 3, ch = c & 7;
            uint4 x = *(const uint4*)&Vt[d * VSTR + ch * 8];
            *(uint4*)(Vb + ((size_t)grp * HD_ + d) * LK_ + blk * BS_ + ch * 8) = x;
        }
    }
}

// ---------------- Pass 2: fused paged prefill attention ----------------
// LDS tiles (48 KB total, no padding, XOR-chunk-swizzled):
//   Ksh[64 tok][128 d]   rows 256 B, 16 chunks of 16 B, phys chunk = c8 ^ (tok&15)
//   Vsh[128 d][64 tok]   rows 128 B,  8 chunks of 16 B, phys chunk = c8 ^ (d&7)
//   Psh[128 row][64 key] rows 128 B,  8 chunks of 16 B, phys chunk = c8 ^ (row&7)
template<bool PREP>
__global__ __launch_bounds__(256, 2)
void paged_attn(const float* __restrict__ q,
                const unsigned short* __restrict__ Kb,
                const unsigned short* __restrict__ Vb,
                const float* __restrict__ kc,
                const float* __restrict__ vc,
                const int* __restrict__ bt,
                float* __restrict__ out)
{
    __shared__ __align__(16) unsigned short Ksh[BS_ * HD_];   // 16384 B
    __shared__ __align__(16) unsigned short Vsh[HD_ * BS_];   // 16384 B
    __shared__ __align__(16) unsigned short Psh[BM_ * BS_];   // 16384 B

    const int tid  = threadIdx.x;
    const int w    = tid >> 6;
    const int lane = tid & 63;
    const int n    = lane & 15;
    const int q4   = lane >> 4;

    // XCD-aware decode: blockIdx.x % 8 == kvh pins each kvh's KV slab to one XCD's L2
    const int gid  = blockIdx.x;           // 512
    const int kvh  = gid & 7;
    const int slot = gid >> 3;
    const int seq  = slot >> 5;
    const int sub  = slot & 31;
    const int head = kvh * 4 + (sub & 3);
    const int m0   = (sub >> 2) * BM_;
    const int r0   = m0 + w * 32;
    const int grp  = seq * NKVH_ + kvh;

    // Q fragments fp32 -> bf16: A[m=lane&15][k=quad*8+j]
    short8 qf[2][4];
#pragma unroll
    for (int rt = 0; rt < 2; ++rt) {
        const size_t base = ((size_t)((seq * LQ_ + r0 + rt * 16 + n) * NH_ + head)) * HD_;
#pragma unroll
        for (int c = 0; c < 4; ++c) {
            float4 a = *(const float4*)(q + base + c * 32 + q4 * 8);
            float4 b = *(const float4*)(q + base + c * 32 + q4 * 8 + 4);
            unsigned short u[8] = {f2bf(a.x), f2bf(a.y), f2bf(a.z), f2bf(a.w),
                                   f2bf(b.x), f2bf(b.y), f2bf(b.z), f2bf(b.w)};
            qf[rt][c] = *(const short8*)u;
        }
    }

    f32x4 acc[2][8];
    f32x4 lf[2];
    float mrow[2][4];
#pragma unroll
    for (int rt = 0; rt < 2; ++rt) {
        lf[rt] = (f32x4){0.f, 0.f, 0.f, 0.f};
#pragma unroll
        for (int dt = 0; dt < 8; ++dt) acc[rt][dt] = (f32x4){0.f, 0.f, 0.f, 0.f};
#pragma unroll
        for (int r = 0; r < 4; ++r) mrow[rt][r] = -1e30f;
    }

    const int nb = (HIST_ + m0 + BM_ - 1) / BS_ + 1;
    const float SC = 0.08838834764831845f * 1.4426950408889634f;  // 1/sqrt(128) * log2(e)

    for (int b = 0; b < nb; ++b) {
        __syncthreads();   // previous iteration's LDS reads complete
        if constexpr (PREP) {
            // async global->LDS, 16 B/lane; source address carries the XOR swizzle
            const size_t kg = ((size_t)grp * LK_ + b * BS_) * HD_;
#pragma unroll
            for (int j = 0; j < 4; ++j) {
                const int row = w * 16 + j * 4 + (lane >> 4);
                const int c8  = (lane & 15) ^ (row & 15);
                cp16(Kb + kg + (size_t)row * HD_ + c8 * 8, &Ksh[(w * 16 + j * 4) * HD_]);
            }
            const size_t vg = (size_t)grp * HD_ * LK_ + b * BS_;
#pragma unroll
            for (int j = 0; j < 4; ++j) {
                const int d  = w * 32 + j * 8 + (lane >> 3);
                const int c8 = (lane & 7) ^ (d & 7);
                cp16(Vb + vg + (size_t)d * LK_ + c8 * 8, &Vsh[(w * 32 + j * 8) * BS_]);
            }
        } else {
            // fallback: direct fp32 gather + cvt into the same swizzled layout
            const int ph = bt[seq * MAXB_ + b];
            const size_t src = ((size_t)ph * BS_ * NKVH_ + kvh) * HD_;
#pragma unroll
            for (int j = 0; j < 4; ++j) {
                const int row = w * 16 + j * 4 + (lane >> 4);
                const int c8  = (lane & 15) ^ (row & 15);
                float4 a = *(const float4*)(kc + src + (size_t)row * (NKVH_ * HD_) + c8 * 8);
                float4 b2 = *(const float4*)(kc + src + (size_t)row * (NKVH_ * HD_) + c8 * 8 + 4);
                unsigned short u[8] = {f2bf(a.x), f2bf(a.y), f2bf(a.z), f2bf(a.w),
                                       f2bf(b2.x), f2bf(b2.y), f2bf(b2.z), f2bf(b2.w)};
                *(short8*)&Ksh[row * HD_ + (lane & 15) * 8] = *(const short8*)u;
            }
#pragma unroll
            for (int j = 0; j < 4; ++j) {
                const int d  = w * 32 + j * 8 + (lane >> 3);
                const int c8 = (lane & 7) ^ (d & 7);
                unsigned short u[8];
#pragma unroll
                for (int i2 = 0; i2 < 8; ++i2)
                    u[i2] = f2bf(vc[src + (size_t)(c8 * 8 + i2) * (NKVH_ * HD_) + d]);
                *(short8*)&Vsh[d * BS_ + (lane & 7) * 8] = *(const short8*)u;
            }
        }
        __syncthreads();   // drains vmcnt(0) -> tiles ready

        if (64 * b <= HIST_ + r0 + 31) {
            // ---- S = Q K^T ----
            f32x4 s[2][4];
#pragma unroll
            for (int rt = 0; rt < 2; ++rt)
#pragma unroll
                for (int kt = 0; kt < 4; ++kt) s[rt][kt] = (f32x4){0.f, 0.f, 0.f, 0.f};
#pragma unroll
            for (int kt = 0; kt < 4; ++kt) {
#pragma unroll
                for (int c = 0; c < 4; ++c) {
                    short8 kf = *(const short8*)&Ksh[(kt * 16 + n) * HD_ + (((c * 4 + q4) ^ n) << 3)];
#pragma unroll
                    for (int rt = 0; rt < 2; ++rt)
                        s[rt][kt] = __builtin_amdgcn_mfma_f32_16x16x32_bf16(qf[rt][c], kf, s[rt][kt], 0, 0, 0);
                }
            }
            const bool needMask = (64 * b + 63 > HIST_ + r0);
#pragma unroll
            for (int rt = 0; rt < 2; ++rt) {
                float mx[4], al[4];
#pragma unroll
                for (int r = 0; r < 4; ++r) mx[r] = -1e30f;
#pragma unroll
                for (int kt = 0; kt < 4; ++kt) {
#pragma unroll
                    for (int r = 0; r < 4; ++r) {
                        float t = s[rt][kt][r] * SC;
                        if (needMask) {
                            const int key = b * 64 + kt * 16 + n;
                            const int row = r0 + rt * 16 + q4 * 4 + r;
                            if (key > HIST_ + row) t = -1e30f;
                        }
                        s[rt][kt][r] = t;
                        mx[r] = fmaxf(mx[r], t);
                    }
                }
                // 16-lane row-max via DPP (VALU pipe, no LDS traffic)
#pragma unroll
                for (int r = 0; r < 4; ++r) {
                    mx[r] = dppmax<0xB1>(mx[r]);    // quad_perm [1,0,3,2]  (xor 1)
                    mx[r] = dppmax<0x4E>(mx[r]);    // quad_perm [2,3,0,1]  (xor 2)
                    mx[r] = dppmax<0x124>(mx[r]);   // row_ror:4
                    mx[r] = dppmax<0x128>(mx[r]);   // row_ror:8
                    const float mn = fmaxf(mrow[rt][r], mx[r]);
                    al[r] = __builtin_amdgcn_exp2f(mrow[rt][r] - mn);
                    mrow[rt][r] = mn;
                }
                // P (bf16) -> LDS, C-layout -> swizzled row-major [row][key]
                const int rbase = w * 32 + rt * 16 + q4 * 4;
#pragma unroll
                for (int kt = 0; kt < 4; ++kt) {
                    const int cb = kt * 2 + (n >> 3);
                    const int ci = n & 7;
#pragma unroll
                    for (int r = 0; r < 4; ++r) {
                        const int row = rbase + r;
                        const float p = __builtin_amdgcn_exp2f(s[rt][kt][r] - mrow[rt][r]);
                        Psh[row * BS_ + ((cb ^ (row & 7)) << 3) + ci] = f2bf(p);
                    }
                }
                // rescale running accumulators only when max actually moved
                if (__any(al[0] != 1.f || al[1] != 1.f || al[2] != 1.f || al[3] != 1.f)) {
#pragma unroll
                    for (int dt = 0; dt < 8; ++dt)
#pragma unroll
                        for (int r = 0; r < 4; ++r) acc[rt][dt][r] *= al[r];
#pragma unroll
                    for (int r = 0; r < 4; ++r) lf[rt][r] *= al[r];
                }
            }
            // ---- O += P V ; l += P 1 ----
            short8 ones;
#pragma unroll
            for (int j = 0; j < 8; ++j) ones[j] = (short)0x3F80;
#pragma unroll
            for (int ks = 0; ks < 2; ++ks) {
                short8 pa[2];
#pragma unroll
                for (int rt = 0; rt < 2; ++rt)
                    pa[rt] = *(const short8*)&Psh[(w * 32 + rt * 16 + n) * BS_ + (((ks * 4 + q4) ^ (n & 7)) << 3)];
#pragma unroll
                for (int rt = 0; rt < 2; ++rt)
                    lf[rt] = __builtin_amdgcn_mfma_f32_16x16x32_bf16(pa[rt], ones, lf[rt], 0, 0, 0);
#pragma unroll
                for (int dt = 0; dt < 8; ++dt) {
                    short8 vf = *(const short8*)&Vsh[(dt * 16 + n) * BS_ + (((ks * 4 + q4) ^ (n & 7)) << 3)];
#pragma unroll
                    for (int rt = 0; rt < 2; ++rt)
                        acc[rt][dt] = __builtin_amdgcn_mfma_f32_16x16x32_bf16(pa[rt], vf, acc[rt][dt], 0, 0, 0);
                }
            }
        }
    }

    // epilogue: O = acc / l (fp32 out)
#pragma unroll
    for (int rt = 0; rt < 2; ++rt) {
        float rl[4];
#pragma unroll
        for (int r = 0; r < 4; ++r) rl[r] = 1.0f / lf[rt][r];
#pragma unroll
        for (int dt = 0; dt < 8; ++dt)
#pragma unroll
            for (int r = 0; r < 4; ++r) {
                const int row = r0 + rt * 16 + q4 * 4 + r;
                out[((size_t)((seq * LQ_ + row) * NH_ + head)) * HD_ + dt * 16 + n] = acc[rt][dt][r] * rl[r];
            }
    }
}

extern "C" void kernel_launch(void* const* d_in, const int* in_sizes, int n_in,
                              void* d_out, int out_size, void* d_ws, size_t ws_size,
                              hipStream_t stream) {
    const float* q  = (const float*)d_in[0];
    const float* kc = (const float*)d_in[1];
    const float* vc = (const float*)d_in[2];
    const int*   bt = (const int*)d_in[5];
    float*      out = (float*)d_out;
    (void)in_sizes; (void)n_in; (void)out_size;

    const size_t kb_elems = (size_t)NS_ * NKVH_ * LK_ * HD_;        // 4.19M
    const size_t need = kb_elems * 2 * sizeof(unsigned short);      // 16.78 MB
    if (ws_size >= need) {
        unsigned short* Kb = (unsigned short*)d_ws;
        unsigned short* Vb = Kb + kb_elems;
        prep_kv<<<1024, 256, 0, stream>>>(kc, vc, bt, Kb, Vb);
        paged_attn<true><<<512, 256, 0, stream>>>(q, Kb, Vb, kc, vc, bt, out);
    } else {
        paged_attn<false><<<512, 256, 0, stream>>>(q, nullptr, nullptr, kc, vc, bt, out);
    }
}

// Round 5
// 207.924 us; speedup vs baseline: 1.4597x; 1.0038x over previous
//
#include <hip/hip_runtime.h>
#include <hip/hip_bf16.h>

// Static problem dims
#define NS_    2
#define LQ_    1024
#define HIST_  1024
#define LK_    2048
#define NH_    32
#define NKVH_  8
#define HD_    128
#define BS_    64      // kv page size
#define BM_    128     // q rows per workgroup
#define MAXB_  32

typedef __attribute__((ext_vector_type(8))) short short8;
typedef __attribute__((ext_vector_type(4))) float f32x4;

#define VSTR 72   // prep-internal V transpose tile stride (16B-aligned rows)

static __device__ __forceinline__ unsigned short f2bf(float x) {
    __hip_bfloat16 h = __float2bfloat16(x);
    return *(unsigned short*)&h;
}

static __device__ __forceinline__ void cp16(const void* g, void* l) {
    __builtin_amdgcn_global_load_lds(
        (const __attribute__((address_space(1))) void*)g,
        (__attribute__((address_space(3))) void*)l, 16, 0, 0);
}

template<int CTRL>
static __device__ __forceinline__ float dppmax(float x) {
    int y = __builtin_amdgcn_update_dpp(0, __float_as_int(x), CTRL, 0xf, 0xf, true);
    return fmaxf(x, __int_as_float(y));
}

// ---------------- Pass 1: gather + fp32->bf16 + V-transpose into workspace ----------------
// Kb[grp][tok][d]  (bf16)   Vb[grp][d][tok]  (bf16, transposed); grp = seq*8+kvh
// One WG per (seq,kvh,blk); all 16 global loads issued before any dependent work (MLP).
__global__ __launch_bounds__(256)
void prep_kv(const float* __restrict__ kc, const float* __restrict__ vc,
             const int* __restrict__ bt,
             unsigned short* __restrict__ Kb, unsigned short* __restrict__ Vb)
{
    __shared__ __align__(16) unsigned short Vt[HD_ * VSTR];
    const int tid = threadIdx.x;
    const int gid = blockIdx.x;            // 512 = seq(2) x kvh(8) x blk(32)
    const int seq = gid >> 8;
    const int kvh = (gid >> 5) & 7;
    const int blk = gid & 31;
    const int ph  = bt[seq * MAXB_ + blk];
    const size_t src = ((size_t)ph * BS_ * NKVH_ + kvh) * HD_;   // float elements
    const int grp = seq * NKVH_ + kvh;
    const int t8 = tid >> 5, q32 = tid & 31;

    float4 kr[8], vr[8];
#pragma unroll
    for (int p = 0; p < 8; ++p)
        kr[p] = *(const float4*)(kc + src + (size_t)(p * 8 + t8) * (NKVH_ * HD_) + q32 * 4);
#pragma unroll
    for (int j = 0; j < 8; ++j)
        vr[j] = *(const float4*)(vc + src + (size_t)(t8 * 8 + j) * (NKVH_ * HD_) + q32 * 4);

    // K: cvt + contiguous store (wave writes 512 B runs)
#pragma unroll
    for (int p = 0; p < 8; ++p) {
        unsigned short u[4] = {f2bf(kr[p].x), f2bf(kr[p].y), f2bf(kr[p].z), f2bf(kr[p].w)};
        *(uint2*)(Kb + ((size_t)grp * LK_ + blk * BS_ + p * 8 + t8) * HD_ + q32 * 4) = *(const uint2*)u;
    }
    // V: register 4-wide transpose via LDS, then contiguous store
#pragma unroll
    for (int w2 = 0; w2 < 4; ++w2) {
        unsigned short row[8];
#pragma unroll
        for (int j = 0; j < 8; ++j) {
            float f = (w2 == 0) ? vr[j].x : (w2 == 1) ? vr[j].y : (w2 == 2) ? vr[j].z : vr[j].w;
            row[j] = f2bf(f);
        }
        *(short8*)&Vt[(q32 * 4 + w2) * VSTR + t8 * 8] = *(const short8*)row;
    }
    __syncthreads();
#pragma unroll
    for (int u = 0; u < 4; ++u) {
        const int c  = tid + 256 * u;      // 0..1023 chunks of 8 elements
        const int d  = c >> 3, ch = c & 7;
        uint4 x = *(const uint4*)&Vt[d * VSTR + ch * 8];
        *(uint4*)(Vb + ((size_t)grp * HD_ + d) * LK_ + blk * BS_ + ch * 8) = x;
    }
}

// ---------------- Pass 2: fused paged prefill attention ----------------
// Double-buffered async staging: one barrier per iteration; cp16 for block b+1
// issues right after the barrier and has the whole compute(b) phase to land.
// LDS 80 KB -> 2 WGs/CU. XOR-chunk swizzle keeps all b128 frag reads conflict-free.
template<bool PREP>
__global__ __launch_bounds__(256, 2)
void paged_attn(const float* __restrict__ q,
                const unsigned short* __restrict__ Kb,
                const unsigned short* __restrict__ Vb,
                const float* __restrict__ kc,
                const float* __restrict__ vc,
                const int* __restrict__ bt,
                float* __restrict__ out)
{
    __shared__ __align__(16) unsigned short Ksh[2][BS_ * HD_];   // 2 x 16384 B
    __shared__ __align__(16) unsigned short Vsh[2][HD_ * BS_];   // 2 x 16384 B
    __shared__ __align__(16) unsigned short Psh[BM_ * BS_];      // 16384 B

    const int tid  = threadIdx.x;
    const int w    = tid >> 6;
    const int lane = tid & 63;
    const int n    = lane & 15;
    const int q4   = lane >> 4;

    // XCD-aware decode (gid%8 = kvh pins KV slab to one XCD's L2) + balanced tile pairing:
    // consecutive slots get tiles (t, 7-t) so co-resident WGs sum to equal work.
    const int gid  = blockIdx.x;           // 512
    const int kvh  = gid & 7;
    const int slot = gid >> 3;
    const int seq  = slot >> 5;
    const int sub  = slot & 31;
    const int e    = sub & 1;
    const int t3   = (sub >> 1) & 7;
    const int hp   = sub >> 4;
    const int head = kvh * 4 + hp * 2 + e;
    const int m0   = (e ? (7 - t3) : t3) * BM_;
    const int r0   = m0 + w * 32;
    const int grp  = seq * NKVH_ + kvh;

    // Q fragments fp32 -> bf16, pre-scaled by 1/sqrt(128)*log2(e): A[m=lane&15][k=quad*8+j]
    const float SC = 0.08838834764831845f * 1.4426950408889634f;
    short8 qf[2][4];
#pragma unroll
    for (int rt = 0; rt < 2; ++rt) {
        const size_t base = ((size_t)((seq * LQ_ + r0 + rt * 16 + n) * NH_ + head)) * HD_;
#pragma unroll
        for (int c = 0; c < 4; ++c) {
            float4 a = *(const float4*)(q + base + c * 32 + q4 * 8);
            float4 b = *(const float4*)(q + base + c * 32 + q4 * 8 + 4);
            unsigned short u[8] = {f2bf(a.x * SC), f2bf(a.y * SC), f2bf(a.z * SC), f2bf(a.w * SC),
                                   f2bf(b.x * SC), f2bf(b.y * SC), f2bf(b.z * SC), f2bf(b.w * SC)};
            qf[rt][c] = *(const short8*)u;
        }
    }

    f32x4 acc[2][8];
    f32x4 lf[2];
    float mrow[2][4];
#pragma unroll
    for (int rt = 0; rt < 2; ++rt) {
        lf[rt] = (f32x4){0.f, 0.f, 0.f, 0.f};
#pragma unroll
        for (int dt = 0; dt < 8; ++dt) acc[rt][dt] = (f32x4){0.f, 0.f, 0.f, 0.f};
#pragma unroll
        for (int r = 0; r < 4; ++r) mrow[rt][r] = -1e30f;
    }

    const int nb = (HIST_ + m0 + BM_ - 1) / BS_ + 1;
    const unsigned short* kSrc = Kb + (size_t)grp * LK_ * HD_;
    const unsigned short* vSrc = Vb + (size_t)grp * HD_ * LK_;

    // async staging: source address carries the XOR swizzle; LDS dest is wave-uniform + lane*16
    const int krow_ = w * 16 + (lane >> 4);          // +j*4
    const int kc8_  = ((lane & 15) ^ (krow_ & 15));
    const int vd_   = w * 32 + (lane >> 3);          // +j*8
    const int vc8_  = ((lane & 7) ^ (vd_ & 7));

    auto issue = [&](int b, int buf) {
#pragma unroll
        for (int j = 0; j < 4; ++j) {
            const int row = krow_ + j * 4;
            const int c8  = (lane & 15) ^ (row & 15);
            cp16(kSrc + ((size_t)b * BS_ + row) * HD_ + c8 * 8, &Ksh[buf][(w * 16 + j * 4) * HD_]);
        }
#pragma unroll
        for (int j = 0; j < 4; ++j) {
            const int d  = vd_ + j * 8;
            const int c8 = (lane & 7) ^ (d & 7);
            cp16(vSrc + (size_t)d * LK_ + b * BS_ + c8 * 8, &Vsh[buf][(w * 32 + j * 8) * BS_]);
        }
    };

    if constexpr (PREP) issue(0, 0);
    short8 ones;
#pragma unroll
    for (int j = 0; j < 8; ++j) ones[j] = (short)0x3F80;

    for (int b = 0; b < nb; ++b) {
        const int cur = PREP ? (b & 1) : 0;
        __syncthreads();   // drains cp16 for buf[cur]; all waves done reading buf[1^cur]
        if constexpr (PREP) {
            if (b + 1 < nb) issue(b + 1, 1 ^ cur);
        } else {
            // fallback: direct fp32 gather + cvt into swizzled layout (2-barrier structure)
            const int ph = bt[seq * MAXB_ + b];
            const size_t src = ((size_t)ph * BS_ * NKVH_ + kvh) * HD_;
#pragma unroll
            for (int j = 0; j < 4; ++j) {
                const int row = w * 16 + j * 4 + (lane >> 4);
                const int c8  = (lane & 15) ^ (row & 15);
                float4 a = *(const float4*)(kc + src + (size_t)row * (NKVH_ * HD_) + c8 * 8);
                float4 b2 = *(const float4*)(kc + src + (size_t)row * (NKVH_ * HD_) + c8 * 8 + 4);
                unsigned short u[8] = {f2bf(a.x), f2bf(a.y), f2bf(a.z), f2bf(a.w),
                                       f2bf(b2.x), f2bf(b2.y), f2bf(b2.z), f2bf(b2.w)};
                *(short8*)&Ksh[0][row * HD_ + (lane & 15) * 8] = *(const short8*)u;
            }
#pragma unroll
            for (int j = 0; j < 4; ++j) {
                const int d  = w * 32 + j * 8 + (lane >> 3);
                const int c8 = (lane & 7) ^ (d & 7);
                unsigned short u[8];
#pragma unroll
                for (int i2 = 0; i2 < 8; ++i2)
                    u[i2] = f2bf(vc[src + (size_t)(c8 * 8 + i2) * (NKVH_ * HD_) + d]);
                *(short8*)&Vsh[0][d * BS_ + (lane & 7) * 8] = *(const short8*)u;
            }
            __syncthreads();
        }

        if (64 * b <= HIST_ + r0 + 31) {
            // ---- S = Q K^T (pre-scaled) ----
            f32x4 s[2][4];
#pragma unroll
            for (int rt = 0; rt < 2; ++rt)
#pragma unroll
                for (int kt = 0; kt < 4; ++kt) s[rt][kt] = (f32x4){0.f, 0.f, 0.f, 0.f};
#pragma unroll
            for (int kt = 0; kt < 4; ++kt) {
#pragma unroll
                for (int c = 0; c < 4; ++c) {
                    short8 kf = *(const short8*)&Ksh[cur][(kt * 16 + n) * HD_ + (((c * 4 + q4) ^ n) << 3)];
#pragma unroll
                    for (int rt = 0; rt < 2; ++rt)
                        s[rt][kt] = __builtin_amdgcn_mfma_f32_16x16x32_bf16(qf[rt][c], kf, s[rt][kt], 0, 0, 0);
                }
            }
            const bool needMask = (64 * b + 63 > HIST_ + r0);
#pragma unroll
            for (int rt = 0; rt < 2; ++rt) {
                float mx[4], al[4];
#pragma unroll
                for (int r = 0; r < 4; ++r) mx[r] = -1e30f;
#pragma unroll
                for (int kt = 0; kt < 4; ++kt) {
#pragma unroll
                    for (int r = 0; r < 4; ++r) {
                        float t = s[rt][kt][r];
                        if (needMask) {
                            const int key = b * 64 + kt * 16 + n;
                            const int row = r0 + rt * 16 + q4 * 4 + r;
                            if (key > HIST_ + row) t = -1e30f;
                        }
                        s[rt][kt][r] = t;
                        mx[r] = fmaxf(mx[r], t);
                    }
                }
                // 16-lane row-max via DPP (VALU pipe)
#pragma unroll
                for (int r = 0; r < 4; ++r) {
                    mx[r] = dppmax<0xB1>(mx[r]);    // quad_perm xor1
                    mx[r] = dppmax<0x4E>(mx[r]);    // quad_perm xor2
                    mx[r] = dppmax<0x124>(mx[r]);   // row_ror:4
                    mx[r] = dppmax<0x128>(mx[r]);   // row_ror:8
                    const float mn = fmaxf(mrow[rt][r], mx[r]);
                    al[r] = __builtin_amdgcn_exp2f(mrow[rt][r] - mn);
                    mrow[rt][r] = mn;
                }
                // P (bf16) -> LDS, C-layout -> swizzled row-major [row][key]
                const int rbase = w * 32 + rt * 16 + q4 * 4;
#pragma unroll
                for (int kt = 0; kt < 4; ++kt) {
                    const int cb = kt * 2 + (n >> 3);
                    const int ci = n & 7;
#pragma unroll
                    for (int r = 0; r < 4; ++r) {
                        const int row = rbase + r;
                        const float p = __builtin_amdgcn_exp2f(s[rt][kt][r] - mrow[rt][r]);
                        Psh[row * BS_ + ((cb ^ (row & 7)) << 3) + ci] = f2bf(p);
                    }
                }
                if (__any(al[0] != 1.f || al[1] != 1.f || al[2] != 1.f || al[3] != 1.f)) {
#pragma unroll
                    for (int dt = 0; dt < 8; ++dt)
#pragma unroll
                        for (int r = 0; r < 4; ++r) acc[rt][dt][r] *= al[r];
#pragma unroll
                    for (int r = 0; r < 4; ++r) lf[rt][r] *= al[r];
                }
            }
            // ---- O += P V ; l += P 1 ----
#pragma unroll
            for (int ks = 0; ks < 2; ++ks) {
                short8 pa[2];
#pragma unroll
                for (int rt = 0; rt < 2; ++rt)
                    pa[rt] = *(const short8*)&Psh[(w * 32 + rt * 16 + n) * BS_ + (((ks * 4 + q4) ^ (n & 7)) << 3)];
#pragma unroll
                for (int rt = 0; rt < 2; ++rt)
                    lf[rt] = __builtin_amdgcn_mfma_f32_16x16x32_bf16(pa[rt], ones, lf[rt], 0, 0, 0);
#pragma unroll
                for (int dt = 0; dt < 8; ++dt) {
                    short8 vf = *(const short8*)&Vsh[cur][(dt * 16 + n) * BS_ + (((ks * 4 + q4) ^ (n & 7)) << 3)];
#pragma unroll
                    for (int rt = 0; rt < 2; ++rt)
                        acc[rt][dt] = __builtin_amdgcn_mfma_f32_16x16x32_bf16(pa[rt], vf, acc[rt][dt], 0, 0, 0);
                }
            }
        }
    }

    // epilogue: O = acc / l (fp32 out)
#pragma unroll
    for (int rt = 0; rt < 2; ++rt) {
        float rl[4];
#pragma unroll
        for (int r = 0; r < 4; ++r) rl[r] = 1.0f / lf[rt][r];
#pragma unroll
        for (int dt = 0; dt < 8; ++dt)
#pragma unroll
            for (int r = 0; r < 4; ++r) {
                const int row = r0 + rt * 16 + q4 * 4 + r;
                out[((size_t)((seq * LQ_ + row) * NH_ + head)) * HD_ + dt * 16 + n] = acc[rt][dt][r] * rl[r];
            }
    }
}

extern "C" void kernel_launch(void* const* d_in, const int* in_sizes, int n_in,
                              void* d_out, int out_size, void* d_ws, size_t ws_size,
                              hipStream_t stream) {
    const float* q  = (const float*)d_in[0];
    const float* kc = (const float*)d_in[1];
    const float* vc = (const float*)d_in[2];
    const int*   bt = (const int*)d_in[5];
    float*      out = (float*)d_out;
    (void)in_sizes; (void)n_in; (void)out_size;

    const size_t kb_elems = (size_t)NS_ * NKVH_ * LK_ * HD_;        // 4.19M
    const size_t need = kb_elems * 2 * sizeof(unsigned short);      // 16.78 MB
    if (ws_size >= need) {
        unsigned short* Kb = (unsigned short*)d_ws;
        unsigned short* Vb = Kb + kb_elems;
        prep_kv<<<512, 256, 0, stream>>>(kc, vc, bt, Kb, Vb);
        paged_attn<true><<<512, 256, 0, stream>>>(q, Kb, Vb, kc, vc, bt, out);
    } else {
        paged_attn<false><<<512, 256, 0, stream>>>(q, nullptr, nullptr, kc, vc, bt, out);
    }
}